// Round 9
// baseline (244.527 us; speedup 1.0000x reference)
//
#include <hip/hip_runtime.h>
#include <cstdint>

typedef unsigned long long ull;
typedef __bf16 bf16x8 __attribute__((ext_vector_type(8)));
typedef float f32x4 __attribute__((ext_vector_type(4)));
typedef float f32x2 __attribute__((ext_vector_type(2)));

#define NPTS 8192
#define NB 2
#define KNN 16
#define DM 128
#define PADK 136

__device__ __forceinline__ float sq3f(float x, float y, float z) {
    return __fadd_rn(__fadd_rn(__fmul_rn(x, x), __fmul_rn(y, y)), __fmul_rn(z, z));
}
__device__ __forceinline__ unsigned ford(unsigned u) {
    return (u & 0x80000000u) ? ~u : (u | 0x80000000u);
}
__device__ __forceinline__ float inv_ford(unsigned f) {
    unsigned u = (f & 0x80000000u) ? (f ^ 0x80000000u) : ~f;
    return __uint_as_float(u);
}
// VOP3P packed f32: one instruction = two independent IEEE-RN f32 ops
// (bit-identical to the scalar pair, so KNN selection is unchanged).
__device__ __forceinline__ f32x2 pk_mul(f32x2 a, f32x2 b) {
    f32x2 d;
    asm("v_pk_mul_f32 %0, %1, %2" : "=v"(d) : "v"(a), "v"(b));
    return d;
}
__device__ __forceinline__ f32x2 pk_add(f32x2 a, f32x2 b) {
    f32x2 d;
    asm("v_pk_add_f32 %0, %1, %2" : "=v"(d) : "v"(a), "v"(b));
    return d;
}

// ---------------------------------------------------------------- KNN
// Wave-cooperative top-16. R8: VALU-issue-bound at 70% with the 16-scalar-op
// dist chain the largest block. This round: pair-layout LDS staging
// (xsA={x0,x1,y0,y1}, xsB={z0,z1,sq0,sq1} for candidates (c, c+64)) feeds
// v_pk_mul/add_f32 -> 8 packed instr for 2 candidates, op-for-op the same
// rounding sequence (x*-2 then add == mul-then-sub exactly). Ballot/pop path
// and seed threshold unchanged (R7/R8-verified).
// Selection bit-identical to jax.lax.top_k ((dist_bits, idx) ascending).
__global__ __launch_bounds__(256) void knn_kernel(const float* __restrict__ xyz,
                                                  int* __restrict__ idx_out) {
    __shared__ float4 xsA[512];
    __shared__ float4 xsB[512];
    const int t = threadIdx.x;
    const int wv = t >> 6, lane = t & 63;
    const int q_id = blockIdx.x * 4 + wv;
    const int b = q_id >> 13;
    const int i = q_id & (NPTS - 1);
    const float* xb = xyz + (size_t)b * NPTS * 3;
    const float qx = xb[3 * i + 0], qy = xb[3 * i + 1], qz = xb[3 * i + 2];
    const float sqi = sq3f(qx, qy, qz);
    const f32x2 qx2 = {qx, qx}, qy2 = {qy, qy}, qz2 = {qz, qz};
    const f32x2 sqi2 = {sqi, sqi}, ntwo2 = {-2.0f, -2.0f};

    // lanes 0..15: sorted top-16 (ascending, lexicographic (ford(d), idx))
    unsigned list_hi = 0xffffffffu, list_lo = 0xffffffffu;
    float thrF = __uint_as_float(0x7f800000u);  // upper bound on current 16th

#define INSERT(FC, CKLO)                                                                 \
    {                                                                                    \
        unsigned ck_hi = ford(__float_as_uint(FC));                                      \
        unsigned ck_lo = (CKLO);                                                         \
        unsigned ph = __shfl_up(list_hi, 1);                                             \
        unsigned pl = __shfl_up(list_lo, 1);                                             \
        bool lt = (ck_hi < list_hi) || (ck_hi == list_hi && ck_lo < list_lo);            \
        bool ge = (lane == 0) || (ck_hi > ph) || (ck_hi == ph && ck_lo >= pl);           \
        list_hi = lt ? (ge ? ck_hi : ph) : list_hi;                                      \
        list_lo = lt ? (ge ? ck_lo : pl) : list_lo;                                      \
        unsigned th = (unsigned)__builtin_amdgcn_readlane((int)list_hi, 15);             \
        th = (th > 0xff800000u) ? 0xff800000u : th; /* sentinel/NaN -> +inf */           \
        thrF = fminf(thrF, inv_ford(th));                                                \
    }

    for (int ch = 0; ch < 8; ++ch) {
        __syncthreads();
#pragma unroll
        for (int e = 0; e < 2; e++) {
            int s = t + e * 256;
            int c0 = ((s >> 6) << 7) + (s & 63);   // pair slot -> candidate (c0, c0+64)
            int g = ch * 1024 + c0;
            float x0 = xb[3 * g + 0], y0 = xb[3 * g + 1], z0 = xb[3 * g + 2];
            float x1 = xb[3 * (g + 64) + 0], y1 = xb[3 * (g + 64) + 1], z1 = xb[3 * (g + 64) + 2];
            xsA[s] = make_float4(x0, x1, y0, y1);  // consecutive lanes -> consecutive float4s
            xsB[s] = make_float4(z0, z1, sq3f(x0, y0, z0), sq3f(x1, y1, z1));
        }
        __syncthreads();
        for (int m = 0; m < 8; m++) {
            const int s = m * 64 + lane;
            float4 A = xsA[s];
            float4 B = xsB[s];
            f32x2 ax = {A.x, A.y}, ay = {A.z, A.w};
            f32x2 bz = {B.x, B.y}, bs = {B.z, B.w};
            // same rounding chain as scalar: p1+p2+p3; (sqi+sq_j) + (-2*dot)
            f32x2 p1 = pk_mul(qx2, ax);
            f32x2 p2 = pk_mul(qy2, ay);
            f32x2 p3 = pk_mul(qz2, bz);
            f32x2 s1 = pk_add(p1, p2);
            f32x2 s2 = pk_add(s1, p3);
            f32x2 num = pk_add(sqi2, bs);
            f32x2 tm = pk_mul(ntwo2, s2);
            f32x2 dd = pk_add(num, tm);
            float dA = dd.x, dB = dd.y;
            if (ch == 0 && m == 0) {
                // seed: max over 16 disjoint 4-lane-group minima (8 cands each)
                // >= true 16th smallest of batch 0 -> exact to prune above it
                float mn = fminf(dA, dB);
                mn = fminf(mn, __shfl_xor(mn, 1));
                mn = fminf(mn, __shfl_xor(mn, 2));
                float mx = mn;
                mx = fmaxf(mx, __shfl_xor(mx, 4));
                mx = fmaxf(mx, __shfl_xor(mx, 8));
                mx = fmaxf(mx, __shfl_xor(mx, 16));
                mx = fmaxf(mx, __shfl_xor(mx, 32));
                thrF = mx;
            }
            ull balA = __ballot(dA <= thrF);
            ull balB = __ballot(dB <= thrF);
            if ((balA | balB) == 0ull) continue;   // wave-uniform branch
            const unsigned jbase = (unsigned)(ch * 1024 + m * 128);
            while (balA) {
                int l = (int)__builtin_ctzll(balA);
                balA &= balA - 1;
                float fc = __uint_as_float(
                    (unsigned)__builtin_amdgcn_readlane(__float_as_int(dA), l));
                if (fc <= thrF) INSERT(fc, jbase + (unsigned)l)
            }
            while (balB) {
                int l = (int)__builtin_ctzll(balB);
                balB &= balB - 1;
                float fc = __uint_as_float(
                    (unsigned)__builtin_amdgcn_readlane(__float_as_int(dB), l));
                if (fc <= thrF) INSERT(fc, jbase + 64u + (unsigned)l)
            }
        }
    }
#undef INSERT
    if (lane < 16)
        idx_out[q_id * 16 + lane] = (int)list_lo;
}

// ---------------------------------------------------------------- weight prep: f32 [k][n] -> bf16 [n][k]
__global__ __launch_bounds__(256) void wprep_kernel(const float* __restrict__ d2,
                                                    const float* __restrict__ g1,
                                                    const float* __restrict__ g2,
                                                    const float* __restrict__ wq,
                                                    const float* __restrict__ wk,
                                                    const float* __restrict__ wv,
                                                    __bf16* __restrict__ d2t,
                                                    __bf16* __restrict__ g1t,
                                                    __bf16* __restrict__ g2t,
                                                    __bf16* __restrict__ wqt,
                                                    __bf16* __restrict__ wkt,
                                                    __bf16* __restrict__ wvt) {
    const int bi = blockIdx.x;
    const float* src = (bi == 0) ? d2 : (bi == 1) ? g1 : (bi == 2) ? g2
                     : (bi == 3) ? wq : (bi == 4) ? wk : wv;
    __bf16* dst = (bi == 0) ? d2t : (bi == 1) ? g1t : (bi == 2) ? g2t
                : (bi == 3) ? wqt : (bi == 4) ? wkt : wvt;
#pragma unroll
    for (int e = 0; e < 64; e++) {
        int id = threadIdx.x + e * 256;
        int k = id >> 7, n = id & 127;
        dst[n * 128 + k] = (__bf16)src[id];
    }
}

#define STAGE_W(SRC)                                                                       \
    {                                                                                      \
        _Pragma("unroll")                                                                  \
        for (int e = 0; e < 8; e++) {                                                      \
            int ch = t + e * 256;                                                          \
            int r = ch >> 4, ck = ch & 15;                                                 \
            *(bf16x8*)&Wb[r * PADK + ck * 8] = *(const bf16x8*)&SRC[r * 128 + ck * 8];     \
        }                                                                                  \
    }

// ---------------------------------------------------------------- fused x + q/k/v
__global__ __launch_bounds__(256, 1) void xqkv_kernel(const float* __restrict__ feats,
                                                      const float* __restrict__ fc1_w,
                                                      const float* __restrict__ fc1_b,
                                                      const __bf16* __restrict__ wqt,
                                                      const __bf16* __restrict__ wkt,
                                                      const __bf16* __restrict__ wvt,
                                                      float* __restrict__ qo,
                                                      float* __restrict__ ko,
                                                      float* __restrict__ vo) {
    __shared__ __align__(16) char lds[52224];
    float* At = (float*)lds;                 // [64 cols][65 rows] f32 (phase A)
    float* Wt = (float*)(lds + 16640);       // [64][128] f32 (phase A)
    __bf16* Ab = (__bf16*)lds;               // [64][PADK] bf16 (phase B)
    __bf16* Wb = (__bf16*)(lds + 17408);     // [128][PADK] bf16 (phase B)
    const int t = threadIdx.x;
    const int base = blockIdx.x * 64;

    // ---- phase A: x = feats@fc1 + b (f32)
#pragma unroll
    for (int e = 0; e < 16; e++) {
        int id = t + e * 256;
        int r = id >> 6, c = id & 63;
        At[c * 65 + r] = feats[(size_t)(base + r) * 64 + c];
    }
#pragma unroll
    for (int e = 0; e < 32; e++) { int id = t + e * 256; Wt[id] = fc1_w[id]; }
    __syncthreads();
    const int r0 = (t >> 4) * 4;
    const int c0 = (t & 15) * 8;
    float acc[4][8];
#pragma unroll
    for (int i = 0; i < 4; i++)
#pragma unroll
        for (int j = 0; j < 8; j++) acc[i][j] = fc1_b[c0 + j];
#pragma unroll 4
    for (int kk = 0; kk < 64; ++kk) {
        float a0 = At[kk * 65 + r0 + 0];
        float a1 = At[kk * 65 + r0 + 1];
        float a2 = At[kk * 65 + r0 + 2];
        float a3 = At[kk * 65 + r0 + 3];
        const float4 w0 = *(const float4*)&Wt[kk * 128 + c0];
        const float4 w1 = *(const float4*)&Wt[kk * 128 + c0 + 4];
        float wj[8] = {w0.x, w0.y, w0.z, w0.w, w1.x, w1.y, w1.z, w1.w};
#pragma unroll
        for (int j = 0; j < 8; j++) {
            acc[0][j] += a0 * wj[j];
            acc[1][j] += a1 * wj[j];
            acc[2][j] += a2 * wj[j];
            acc[3][j] += a3 * wj[j];
        }
    }
    __syncthreads();   // all reads of At/Wt done; union region reusable

    // ---- x -> bf16 tile
#pragma unroll
    for (int i = 0; i < 4; i++)
#pragma unroll
        for (int j = 0; j < 8; j++)
            Ab[(r0 + i) * PADK + c0 + j] = (__bf16)acc[i][j];
    STAGE_W(wqt)
    __syncthreads();

    // ---- phase B: 3 MFMA GEMMs
    const int lane = t & 63;
    const int lr = lane & 15, lg = lane >> 4;
    const int rbase = (t >> 6) * 16;

#define QGEMM(ACC, OUT)                                                                    \
    {                                                                                      \
        f32x4 ACC[8];                                                                      \
        _Pragma("unroll")                                                                  \
        for (int ct = 0; ct < 8; ct++) ACC[ct] = (f32x4){0.f, 0.f, 0.f, 0.f};              \
        _Pragma("unroll")                                                                  \
        for (int kt = 0; kt < 4; kt++) {                                                   \
            const int ko = kt * 32 + 8 * lg;                                               \
            bf16x8 a0 = *(const bf16x8*)&Ab[(rbase + lr) * PADK + ko];                     \
            _Pragma("unroll")                                                              \
            for (int ct = 0; ct < 8; ct++) {                                               \
                bf16x8 bv = *(const bf16x8*)&Wb[(ct * 16 + lr) * PADK + ko];               \
                ACC[ct] = __builtin_amdgcn_mfma_f32_16x16x32_bf16(a0, bv, ACC[ct], 0, 0, 0); \
            }                                                                              \
        }                                                                                  \
        _Pragma("unroll")                                                                  \
        for (int ct = 0; ct < 8; ct++)                                                     \
            _Pragma("unroll")                                                              \
            for (int e = 0; e < 4; e++)                                                    \
                OUT[(size_t)(base + rbase + 4 * lg + e) * 128 + ct * 16 + lr] = ACC[ct][e]; \
    }

    QGEMM(accq, qo)
    __syncthreads();
    STAGE_W(wkt)
    __syncthreads();
    QGEMM(acck, ko)
    __syncthreads();
    STAGE_W(wvt)
    __syncthreads();
    QGEMM(accv, vo)
#undef QGEMM
}

// MFMA K-loop over K=128: contiguous-8-per-lane fragments (m91/m92-verified convention)
#define DO_GEMM(ACC0, ACC1, WPTR)                                                          \
    {                                                                                      \
        _Pragma("unroll")                                                                  \
        for (int kt = 0; kt < 4; kt++) {                                                   \
            const int ko = kt * 32 + 8 * lg;                                               \
            bf16x8 a0 = *(const bf16x8*)&Ab[(rbase + lr) * PADK + ko];                     \
            bf16x8 a1 = *(const bf16x8*)&Ab[(rbase + 16 + lr) * PADK + ko];                \
            _Pragma("unroll")                                                              \
            for (int ct = 0; ct < 8; ct++) {                                               \
                bf16x8 bv = *(const bf16x8*)&WPTR[(ct * 16 + lr) * PADK + ko];             \
                ACC0[ct] = __builtin_amdgcn_mfma_f32_16x16x32_bf16(a0, bv, ACC0[ct], 0, 0, 0); \
                ACC1[ct] = __builtin_amdgcn_mfma_f32_16x16x32_bf16(a1, bv, ACC1[ct], 0, 0, 0); \
            }                                                                              \
        }                                                                                  \
    }

// ---------------------------------------------------------------- fused k3+k4+k5
__global__ __launch_bounds__(256, 2) void k345_kernel(const float* __restrict__ xyz,
                                                      const int* __restrict__ idxw,
                                                      const float* __restrict__ q,
                                                      const float* __restrict__ xk,
                                                      const float* __restrict__ xv,
                                                      const float* __restrict__ d1,
                                                      const float* __restrict__ bd1,
                                                      const float* __restrict__ bd2,
                                                      const float* __restrict__ bg1,
                                                      const float* __restrict__ bg2,
                                                      const __bf16* __restrict__ d2t,
                                                      const __bf16* __restrict__ g1t,
                                                      const __bf16* __restrict__ g2t,
                                                      float* __restrict__ attn,
                                                      float* __restrict__ res_pre) {
    __shared__ __bf16 Ab[128 * PADK];
    __shared__ __bf16 Wb[128 * PADK];
    __shared__ float rels[128 * 4];
    __shared__ int jrow[128];
    __shared__ float d1s[3 * 128];
    __shared__ float bd1s[128], bd2s[128], bg1s[128], bg2s[128];

    const int t = threadIdx.x;
    const int wv = t >> 6;
    const int lane = t & 63;
    const int lr = lane & 15, lg = lane >> 4;
    const int R0 = blockIdx.x * 128;
    const int b = R0 >> 17;
    const int rbase = wv * 32;

#pragma unroll
    for (int e = 0; e < 2; e++) { int id = t + e * 256; if (id < 384) d1s[id] = d1[id]; }
    if (t < 128) {
        bd1s[t] = bd1[t]; bd2s[t] = bd2[t]; bg1s[t] = bg1[t]; bg2s[t] = bg2[t];
    } else {
        int r = t - 128;
        int j = idxw[R0 + r];
        jrow[r] = j;
        const float* pn = xyz + (size_t)((R0 + r) >> 4) * 3;
        const float* pj = xyz + (size_t)((b << 13) + j) * 3;
        rels[r * 4 + 0] = pn[0] - pj[0];
        rels[r * 4 + 1] = pn[1] - pj[1];
        rels[r * 4 + 2] = pn[2] - pj[2];
    }
    STAGE_W(d2t)
    __syncthreads();

    // T = relu(rel@d1 + bd1) -> Ab (bf16)
    {
        const int c = t & 127;
        const float w0 = d1s[c], w1 = d1s[128 + c], w2 = d1s[256 + c], bb = bd1s[c];
#pragma unroll
        for (int e = 0; e < 64; e++) {
            int r = (t >> 7) + e * 2;
            float v = fmaf(rels[r * 4 + 2], w2,
                      fmaf(rels[r * 4 + 1], w1, fmaf(rels[r * 4 + 0], w0, bb)));
            Ab[r * PADK + c] = (__bf16)fmaxf(v, 0.0f);
        }
    }
    __syncthreads();

    // GEMM1: pos = relu(T@d2 + bd2), kept in registers for h AND the value path
    f32x4 acc0[8], acc1[8];
#pragma unroll
    for (int ct = 0; ct < 8; ct++) {
        float bb = bd2s[ct * 16 + lr];
        acc0[ct] = (f32x4){bb, bb, bb, bb};
        acc1[ct] = acc0[ct];
    }
    DO_GEMM(acc0, acc1, Wb)
    f32x4 pos0[8], pos1[8];
#pragma unroll
    for (int ct = 0; ct < 8; ct++) {
#pragma unroll
        for (int e = 0; e < 4; e++) {
            pos0[ct][e] = fmaxf(acc0[ct][e], 0.0f);
            pos1[ct][e] = fmaxf(acc1[ct][e], 0.0f);
        }
    }

    // h = pos + q - k_nbr  -> Ab (bf16)   [own rows only]
#pragma unroll
    for (int rt = 0; rt < 2; rt++) {
        const int rloc = rbase + rt * 16 + 4 * lg;
        const size_t qbase = (size_t)((R0 + rloc) >> 4) * 128;
        const int j0 = jrow[rloc + 0], j1 = jrow[rloc + 1];
        const int j2 = jrow[rloc + 2], j3 = jrow[rloc + 3];
        const size_t kb0 = (size_t)((b << 13) + j0) * 128;
        const size_t kb1 = (size_t)((b << 13) + j1) * 128;
        const size_t kb2 = (size_t)((b << 13) + j2) * 128;
        const size_t kb3 = (size_t)((b << 13) + j3) * 128;
        f32x4* posR = rt ? pos1 : pos0;
#pragma unroll
        for (int ct = 0; ct < 8; ct++) {
            const int c = ct * 16 + lr;
            const float qv = q[qbase + c];
            f32x4 p = posR[ct];
            Ab[(rloc + 0) * PADK + c] = (__bf16)(p[0] + qv - xk[kb0 + c]);
            Ab[(rloc + 1) * PADK + c] = (__bf16)(p[1] + qv - xk[kb1 + c]);
            Ab[(rloc + 2) * PADK + c] = (__bf16)(p[2] + qv - xk[kb2 + c]);
            Ab[(rloc + 3) * PADK + c] = (__bf16)(p[3] + qv - xk[kb3 + c]);
        }
    }
    __syncthreads();
    STAGE_W(g1t)
    __syncthreads();

    // GEMM2: u = relu(h@g1 + bg1) -> Ab (bf16)
#pragma unroll
    for (int ct = 0; ct < 8; ct++) {
        float bb = bg1s[ct * 16 + lr];
        acc0[ct] = (f32x4){bb, bb, bb, bb};
        acc1[ct] = acc0[ct];
    }
    DO_GEMM(acc0, acc1, Wb)
#pragma unroll
    for (int rt = 0; rt < 2; rt++) {
        const int rloc = rbase + rt * 16 + 4 * lg;
        f32x4* accR = rt ? acc1 : acc0;
#pragma unroll
        for (int ct = 0; ct < 8; ct++) {
            const int c = ct * 16 + lr;
            f32x4 p = accR[ct];
            Ab[(rloc + 0) * PADK + c] = (__bf16)fmaxf(p[0], 0.0f);
            Ab[(rloc + 1) * PADK + c] = (__bf16)fmaxf(p[1], 0.0f);
            Ab[(rloc + 2) * PADK + c] = (__bf16)fmaxf(p[2], 0.0f);
            Ab[(rloc + 3) * PADK + c] = (__bf16)fmaxf(p[3], 0.0f);
        }
    }
    __syncthreads();
    STAGE_W(g2t)
    __syncthreads();

    // GEMM3: logits = u@g2 + bg2 ; softmax over 16 neighbors ;
    // then res_pre = sum_k attn*(v+pos)
#pragma unroll
    for (int ct = 0; ct < 8; ct++) {
        float bb = bg2s[ct * 16 + lr];
        acc0[ct] = (f32x4){bb, bb, bb, bb};
        acc1[ct] = acc0[ct];
    }
    DO_GEMM(acc0, acc1, Wb)
    const float scale = 0.08838834764831845f; /* 1/sqrt(128) */
#pragma unroll
    for (int rt = 0; rt < 2; rt++) {
        const int rloc = rbase + rt * 16 + 4 * lg;
        const int j0 = jrow[rloc + 0], j1 = jrow[rloc + 1];
        const int j2 = jrow[rloc + 2], j3 = jrow[rloc + 3];
        const size_t vb0 = (size_t)((b << 13) + j0) * 128;
        const size_t vb1 = (size_t)((b << 13) + j1) * 128;
        const size_t vb2 = (size_t)((b << 13) + j2) * 128;
        const size_t vb3 = (size_t)((b << 13) + j3) * 128;
        f32x4* accR = rt ? acc1 : acc0;
        f32x4* posR = rt ? pos1 : pos0;
#pragma unroll
        for (int ct = 0; ct < 8; ct++) {
            const int c = ct * 16 + lr;
            f32x4 p = accR[ct];
            float l0 = p[0] * scale, l1 = p[1] * scale, l2 = p[2] * scale, l3 = p[3] * scale;
            float m = fmaxf(fmaxf(l0, l1), fmaxf(l2, l3));
            m = fmaxf(m, __shfl_xor(m, 16));
            m = fmaxf(m, __shfl_xor(m, 32));
            float e0 = __expf(l0 - m), e1 = __expf(l1 - m);
            float e2 = __expf(l2 - m), e3 = __expf(l3 - m);
            float s = (e0 + e1) + (e2 + e3);
            s += __shfl_xor(s, 16);
            s += __shfl_xor(s, 32);
            float inv = 1.0f / s;
            float a0 = e0 * inv, a1 = e1 * inv, a2 = e2 * inv, a3 = e3 * inv;
            size_t ob = (size_t)(R0 + rloc) * 128 + c;
            attn[ob + 0 * 128] = a0;
            attn[ob + 1 * 128] = a1;
            attn[ob + 2 * 128] = a2;
            attn[ob + 3 * 128] = a3;
            f32x4 pp = posR[ct];
            float r = a0 * (xv[vb0 + c] + pp[0])
                    + a1 * (xv[vb1 + c] + pp[1])
                    + a2 * (xv[vb2 + c] + pp[2])
                    + a3 * (xv[vb3 + c] + pp[3]);
            r += __shfl_xor(r, 16);
            r += __shfl_xor(r, 32);
            if (lg == 0)
                res_pre[(size_t)((R0 >> 4) + wv * 2 + rt) * 128 + c] = r;
        }
    }
}

// ---------------------------------------------------------------- res = res_pre@fc2 + b + features
__global__ __launch_bounds__(256, 1) void k6_kernel(const float* __restrict__ res_pre,
                                                    const float* __restrict__ w,
                                                    const float* __restrict__ bias,
                                                    const float* __restrict__ feats,
                                                    float* __restrict__ res_out) {
    __shared__ float At[128 * 65];
    __shared__ __align__(16) float Wt[128 * 64];
    const int t = threadIdx.x;
    const int base = blockIdx.x * 64;
#pragma unroll
    for (int e = 0; e < 32; e++) {
        int id = t + e * 256;
        int r = id >> 7, c = id & 127;
        At[c * 65 + r] = res_pre[(size_t)(base + r) * 128 + c];
    }
#pragma unroll
    for (int e = 0; e < 32; e++) { int id = t + e * 256; Wt[id] = w[id]; }
    __syncthreads();
    const int r0 = (t >> 4) * 4;
    const int c0 = (t & 15) * 4;
    float acc[4][4];
#pragma unroll
    for (int i = 0; i < 4; i++)
#pragma unroll
        for (int j = 0; j < 4; j++) acc[i][j] = bias[c0 + j];
#pragma unroll 4
    for (int kk = 0; kk < 128; ++kk) {
        float a0 = At[kk * 65 + r0 + 0];
        float a1 = At[kk * 65 + r0 + 1];
        float a2 = At[kk * 65 + r0 + 2];
        float a3 = At[kk * 65 + r0 + 3];
        const float4 w0 = *(const float4*)&Wt[kk * 64 + c0];
        float wj[4] = {w0.x, w0.y, w0.z, w0.w};
#pragma unroll
        for (int j = 0; j < 4; j++) {
            acc[0][j] += a0 * wj[j];
            acc[1][j] += a1 * wj[j];
            acc[2][j] += a2 * wj[j];
            acc[3][j] += a3 * wj[j];
        }
    }
#pragma unroll
    for (int i = 0; i < 4; i++)
#pragma unroll
        for (int j = 0; j < 4; j++)
            res_out[(size_t)(base + r0 + i) * 64 + c0 + j] =
                acc[i][j] + feats[(size_t)(base + r0 + i) * 64 + c0 + j];
}

extern "C" void kernel_launch(void* const* d_in, const int* in_sizes, int n_in,
                              void* d_out, int out_size, void* d_ws, size_t ws_size,
                              hipStream_t stream) {
    (void)in_sizes; (void)n_in; (void)out_size; (void)ws_size;
    const float* xyz   = (const float*)d_in[0];
    const float* feats = (const float*)d_in[2];
    const float* fc1_w = (const float*)d_in[3];
    const float* fc1_b = (const float*)d_in[4];
    const float* fc2_w = (const float*)d_in[5];
    const float* fc2_b = (const float*)d_in[6];
    const float* g1    = (const float*)d_in[7];
    const float* bg1   = (const float*)d_in[8];
    const float* g2    = (const float*)d_in[9];
    const float* bg2   = (const float*)d_in[10];
    const float* d1    = (const float*)d_in[11];
    const float* bd1   = (const float*)d_in[12];
    const float* d2    = (const float*)d_in[13];
    const float* bd2   = (const float*)d_in[14];
    const float* wq    = (const float*)d_in[15];
    const float* wk    = (const float*)d_in[16];
    const float* wv    = (const float*)d_in[17];

    int* idxw   = (int*)d_ws;
    float* qbuf = (float*)((char*)d_ws + (1 << 20));
    float* kbuf = qbuf + 2097152;
    float* vbuf = kbuf + 2097152;
    float* rpre = vbuf + 2097152;
    __bf16* d2t = (__bf16*)(rpre + 2097152);
    __bf16* g1t = d2t + 16384;
    __bf16* g2t = g1t + 16384;
    __bf16* wqt = g2t + 16384;
    __bf16* wkt = wqt + 16384;
    __bf16* wvt = wkt + 16384;

    float* res_out = (float*)d_out;
    float* attn    = res_out + 1048576;

    wprep_kernel<<<6, 256, 0, stream>>>(d2, g1, g2, wq, wk, wv,
                                        d2t, g1t, g2t, wqt, wkt, wvt);
    knn_kernel<<<4096, 256, 0, stream>>>(xyz, idxw);
    xqkv_kernel<<<256, 256, 0, stream>>>(feats, fc1_w, fc1_b, wqt, wkt, wvt,
                                         qbuf, kbuf, vbuf);
    k345_kernel<<<2048, 256, 0, stream>>>(xyz, idxw, qbuf, kbuf, vbuf, d1, bd1, bd2, bg1, bg2,
                                          d2t, g1t, g2t, attn, rpre);
    k6_kernel<<<256, 256, 0, stream>>>(rpre, fc2_w, fc2_b, feats, res_out);
}